// Round 1
// baseline (507.719 us; speedup 1.0000x reference)
//
#include <hip/hip_runtime.h>

// Bidirectional LSTM, B=256, T=1024, V=6, D=64, U=64; out = last-step
// concat(h_f, h_b) @ Wd + bd, shape (B,1).
// Reductions: backward dir = ONE step from h0=0 (Wr_b dead); V=6 -> xproj is
// a 6-entry table; mask = 6-bit scalar.
// R12 (4 waves + dpp reduce + per-step barrier): 296us. Counters: VALUBusy 47%,
// per-step ~650 cyc but per-SIMD issue only ~120 cyc -> barrier + LDS latency
// + reduce-chain dominate.
// R13: SINGLE-WAVE step. 64 threads/block, lane u owns unit u's 4 gate
// columns (Wr_f columns in 128 f16-pair VGPRs, 128 dot2/step = issue floor).
// No __syncthreads in the whole 1024-step loop (same-wave in-order DS makes
// the h write->broadcast-read safe; double-buffered anyway). No cross-lane
// reduction: each lane does its own dots, activations, c/h update. h exchange
// = 1 ds_write_b16 + 8 broadcast ds_read_b128. proj stored [v][u][4] so zcur
// is one ds_read_b128/lane. Backward step + proj build also per-lane.

constexpr int kB = 256;
constexpr int kT = 1024;
constexpr int kV = 6;
constexpr int kD = 64;
constexpr int kU = 64;
constexpr int kG = 256; // 4*U gate columns

#define LOG2E 1.44269504f

typedef _Float16 v2h __attribute__((ext_vector_type(2)));

__device__ __forceinline__ float fast_rcp(float x) { return __builtin_amdgcn_rcpf(x); }
__device__ __forceinline__ float exp2_f(float x)   { return __builtin_amdgcn_exp2f(x); }
__device__ __forceinline__ float sig_f(float z)  { return fast_rcp(1.0f + exp2_f(-LOG2E * z)); }
__device__ __forceinline__ float tanh_f(float z) { return 2.0f * fast_rcp(1.0f + exp2_f(-2.0f * LOG2E * z)) - 1.0f; }

__device__ __forceinline__ v2h as_v2h(float x) { return __builtin_bit_cast(v2h, x); }

__global__ __launch_bounds__(64, 1) void bilstm_last_kernel(
    const int*   __restrict__ tokens, // (B,T)
    const float* __restrict__ emb,    // (6,64)
    const float* __restrict__ Wk_f,   // (64,256)
    const float* __restrict__ Wr_f,   // (64,256)
    const float* __restrict__ b_f,    // (256)
    const float* __restrict__ Wk_b,   // (64,256)
    const float* __restrict__ b_b,    // (256)
    const float* __restrict__ Wd,     // (128)
    const float* __restrict__ bd,     // (1)
    float*       __restrict__ out)    // (B)
{
    __shared__ float s_emb[kV * kD];
    __shared__ float s_projPP[kV * kU * 4];          // [v][u][gate] f32
    __shared__ int   __align__(16) s_tok[kT];
    __shared__ _Float16 __align__(16) s_hh[2][kU];   // double-buffered h (f16)

    const int b = blockIdx.x;
    const int l = threadIdx.x;   // lane 0..63 == unit id

    // ---- stage emb + tokens (single wave: no barriers needed anywhere) ----
#pragma unroll
    for (int i = 0; i < kV * kD; i += 64) s_emb[i + l] = emb[i + l];
    {
        const int4* src = (const int4*)(tokens + b * kT);
        int4* dst = (int4*)s_tok;
#pragma unroll
        for (int i = 0; i < 4; ++i) dst[64 * i + l] = src[64 * i + l];
    }
    s_hh[0][l] = (_Float16)0.f;
    s_hh[1][l] = (_Float16)0.f;

    // ---- 6-bit mask, scalarized: bit v = any(emb[v][:] != 0) ----
    unsigned int mbv = 0;
#pragma unroll
    for (int v = 0; v < kV; ++v) {
        const unsigned long long bb = __ballot(s_emb[v * kD + l] != 0.0f);
        mbv |= (bb != 0ull) ? (1u << v) : 0u;
    }
    const unsigned int smb = __builtin_amdgcn_readfirstlane(mbv);

    const int tokL = __builtin_amdgcn_readfirstlane(s_tok[kT - 1]);

    // ---- proj tables: lane l computes columns g*64+l, g=0..3, all 6 tokens,
    //      plus the backward proj at the last token ----
    float af[kV][4];
    float ab4[4];
#pragma unroll
    for (int g = 0; g < 4; ++g) {
        const float bf = b_f[g * kU + l];
#pragma unroll
        for (int v = 0; v < kV; ++v) af[v][g] = bf;
        ab4[g] = b_b[g * kU + l];
    }
#pragma unroll 4
    for (int d = 0; d < kD; ++d) {
        const float e0 = s_emb[0 * kD + d], e1 = s_emb[1 * kD + d];
        const float e2 = s_emb[2 * kD + d], e3 = s_emb[3 * kD + d];
        const float e4 = s_emb[4 * kD + d], e5 = s_emb[5 * kD + d];
        const float eb = s_emb[tokL * kD + d];
#pragma unroll
        for (int g = 0; g < 4; ++g) {
            const float wkf = Wk_f[d * kG + g * kU + l];
            const float wkb = Wk_b[d * kG + g * kU + l];
            af[0][g] = fmaf(e0, wkf, af[0][g]);
            af[1][g] = fmaf(e1, wkf, af[1][g]);
            af[2][g] = fmaf(e2, wkf, af[2][g]);
            af[3][g] = fmaf(e3, wkf, af[3][g]);
            af[4][g] = fmaf(e4, wkf, af[4][g]);
            af[5][g] = fmaf(e5, wkf, af[5][g]);
            ab4[g]   = fmaf(eb, wkb, ab4[g]);
        }
    }
#pragma unroll
    for (int v = 0; v < kV; ++v) {
        float4 t4;
        t4.x = af[v][0]; t4.y = af[v][1]; t4.z = af[v][2]; t4.w = af[v][3];
        ((float4*)s_projPP)[v * kU + l] = t4;
    }

    // ---- backward single step (per-lane, no LDS): c0=0 -> f dead ----
    float hb_val;
    {
        const float ib = sig_f(ab4[0]);
        const float gb = tanh_f(ab4[2]);
        const float ob = sig_f(ab4[3]);
        const float cb = ib * gb;
        const float hb = ob * tanh_f(cb);
        hb_val = ((smb >> tokL) & 1) ? hb : 0.0f;
    }

    // ---- recurrent weights: lane l holds full columns g*64+l as f16 pairs
    //      (4 gates x 32 v2h = 128 VGPRs), coalesced loads per (p,g) ----
    v2h wh[4][32];
#pragma unroll
    for (int g = 0; g < 4; ++g)
#pragma unroll
        for (int p = 0; p < 32; ++p) {
            wh[g][p].x = (_Float16)Wr_f[(2 * p + 0) * kG + g * kU + l];
            wh[g][p].y = (_Float16)Wr_f[(2 * p + 1) * kG + g * kU + l];
        }

    float c = 0.0f, hreg = 0.0f;

    // ---- scalar token pipeline, depth 2 ----
    int stok0 = __builtin_amdgcn_readfirstlane(s_tok[0]);
    float4 zcur = ((const float4*)s_projPP)[stok0 * kU + l];
    int mskc = (smb >> stok0) & 1;
    int stokA = __builtin_amdgcn_readfirstlane(s_tok[1]);

    // per gate: 32 dot2 as 2 chains of depth 16, seeded with the proj value
#define DOTG(g, seed, zout)                                                   \
    {                                                                         \
        float pa = __builtin_amdgcn_fdot2(H[0], wh[g][0], (seed), false);     \
        float pb = __builtin_amdgcn_fdot2(H[1], wh[g][1], 0.0f, false);       \
        _Pragma("unroll")                                                     \
        for (int j = 1; j < 16; ++j) {                                        \
            pa = __builtin_amdgcn_fdot2(H[2*j],   wh[g][2*j],   pa, false);   \
            pb = __builtin_amdgcn_fdot2(H[2*j+1], wh[g][2*j+1], pb, false);   \
        }                                                                     \
        zout = pa + pb;                                                       \
    }

#define STEP(RP, WP, TT)                                                      \
    {                                                                         \
        /* h broadcast: all lanes read the same 128B -> conflict-free */      \
        const float4* hp = (const float4*)s_hh[RP];                           \
        const float4 hv0 = hp[0], hv1 = hp[1], hv2 = hp[2], hv3 = hp[3];      \
        const float4 hv4 = hp[4], hv5 = hp[5], hv6 = hp[6], hv7 = hp[7];      \
        /* prefetches queued behind h; consumed next step */                  \
        const int   vtokB = s_tok[((TT) + 2) & (kT - 1)];                     \
        const float4 znext = ((const float4*)s_projPP)[stokA * kU + l];       \
        const int   mskn = (int)((smb >> stokA) & 1);                         \
        v2h H[32];                                                            \
        H[0]=as_v2h(hv0.x);  H[1]=as_v2h(hv0.y);  H[2]=as_v2h(hv0.z);  H[3]=as_v2h(hv0.w);  \
        H[4]=as_v2h(hv1.x);  H[5]=as_v2h(hv1.y);  H[6]=as_v2h(hv1.z);  H[7]=as_v2h(hv1.w);  \
        H[8]=as_v2h(hv2.x);  H[9]=as_v2h(hv2.y);  H[10]=as_v2h(hv2.z); H[11]=as_v2h(hv2.w); \
        H[12]=as_v2h(hv3.x); H[13]=as_v2h(hv3.y); H[14]=as_v2h(hv3.z); H[15]=as_v2h(hv3.w); \
        H[16]=as_v2h(hv4.x); H[17]=as_v2h(hv4.y); H[18]=as_v2h(hv4.z); H[19]=as_v2h(hv4.w); \
        H[20]=as_v2h(hv5.x); H[21]=as_v2h(hv5.y); H[22]=as_v2h(hv5.z); H[23]=as_v2h(hv5.w); \
        H[24]=as_v2h(hv6.x); H[25]=as_v2h(hv6.y); H[26]=as_v2h(hv6.z); H[27]=as_v2h(hv6.w); \
        H[28]=as_v2h(hv7.x); H[29]=as_v2h(hv7.y); H[30]=as_v2h(hv7.z); H[31]=as_v2h(hv7.w); \
        float zi, zf, zg, zo;                                                 \
        DOTG(0, zcur.x, zi)                                                   \
        DOTG(1, zcur.y, zf)                                                   \
        DOTG(2, zcur.z, zg)                                                   \
        DOTG(3, zcur.w, zo)                                                   \
        const float ai  = sig_f(zi);                                          \
        const float afv = sig_f(zf);                                          \
        const float ag  = tanh_f(zg);                                         \
        const float ao  = sig_f(zo);                                          \
        const float cn = fmaf(afv, c, ai * ag);                               \
        const float hn = ao * tanh_f(cn);                                     \
        if (mskc) { c = cn; hreg = hn; }   /* uniform branch */               \
        s_hh[WP][l] = (_Float16)hreg;                                         \
        zcur = znext; mskc = mskn;                                            \
        stokA = __builtin_amdgcn_readfirstlane(vtokB);                        \
    }

    for (int t = 0; t < kT; t += 2) {
        STEP(0, 1, t)
        STEP(1, 0, t + 1)
    }
#undef STEP
#undef DOTG

    // ---- epilogue: lane l holds exact f32 h_f[l] and h_b[l] ----
    float v = hreg * Wd[l] + hb_val * Wd[kU + l];
#pragma unroll
    for (int off = 32; off > 0; off >>= 1) v += __shfl_down(v, off, 64);
    if (l == 0) out[b] = v + bd[0];
}

extern "C" void kernel_launch(void* const* d_in, const int* in_sizes, int n_in,
                              void* d_out, int out_size, void* d_ws, size_t ws_size,
                              hipStream_t stream) {
    const int*   tokens = (const int*)d_in[0];
    const float* emb    = (const float*)d_in[1];
    const float* Wk_f   = (const float*)d_in[2];
    const float* Wr_f   = (const float*)d_in[3];
    const float* b_f    = (const float*)d_in[4];
    const float* Wk_b   = (const float*)d_in[5];
    // d_in[6] = Wr_b: unused (backward runs one step from h0=0)
    const float* b_b    = (const float*)d_in[7];
    const float* Wd     = (const float*)d_in[8];
    const float* bd     = (const float*)d_in[9];
    float* out = (float*)d_out;

    bilstm_last_kernel<<<kB, 64, 0, stream>>>(
        tokens, emb, Wk_f, Wr_f, b_f, Wk_b, b_b, Wd, bd, out);
}